// Round 2
// baseline (356.024 us; speedup 1.0000x reference)
//
#include <hip/hip_runtime.h>
#include <hip/hip_bf16.h>
#include <hip/hip_cooperative_groups.h>

namespace cg = cooperative_groups;

typedef __attribute__((ext_vector_type(8))) short short8;
typedef __attribute__((ext_vector_type(4))) float f32x4;
typedef __attribute__((address_space(1))) const void gvoid_t;
typedef __attribute__((address_space(3))) void lvoid_t;

#define NB 4096   // B
#define DD 256    // D
#define TWOB 8192
#define NTILES 2080u  // 64*65/2 symmetric 128x128 tiles

__device__ __forceinline__ unsigned short f2bf(float f) {
  unsigned int u = __float_as_uint(f);
  u += 0x7fffu + ((u >> 16) & 1u);
  return (unsigned short)(u >> 16);
}
__device__ __forceinline__ float bf2f(unsigned short s) {
  return __uint_as_float(((unsigned int)s) << 16);
}

// ws float layout: [0..8191] den, [8192..9215] vsum, [9216..9231] scal
//   scal[0]=psum, scal[1]=lsum, scal[2..5]=counts, scal[8]=tile counter (u32)
__global__ __launch_bounds__(256, 3) void fused_kernel(const float* __restrict__ zi,
                                                       const float* __restrict__ zj,
                                                       const int* __restrict__ sf,
                                                       float* __restrict__ wsf,
                                                       unsigned short* __restrict__ znb,
                                                       float* __restrict__ out) {
  __shared__ __align__(16) unsigned short As[2][4096];  // 2 x 8KB
  __shared__ __align__(16) unsigned short Bs[2][4096];
  __shared__ float sred[256];
  __shared__ unsigned sh_t;

  float* den = wsf;
  float* vsum = wsf + 8192;
  float* scal = wsf + 9216;
  unsigned* counter = (unsigned*)(scal + 8);

  const int tid = threadIdx.x;
  const int lane = tid & 63, wave = tid >> 6;

  // ---------------- phase 0+1: zero ws; normalize -> znb; pos partials ----
  {
    int idx = blockIdx.x * 256 + tid;
    if (idx < 9232) wsf[idx] = 0.f;
  }
  float posacc = 0.f;
  {
    int gw = blockIdx.x * 4 + wave;
    int nw = gridDim.x * 4;
    for (int i = gw; i < NB; i += nw) {
      float4 a = ((const float4*)(zi + (size_t)i * DD))[lane];
      float4 b = ((const float4*)(zj + (size_t)i * DD))[lane];
      float sa = a.x * a.x + a.y * a.y + a.z * a.z + a.w * a.w;
      float sb = b.x * b.x + b.y * b.y + b.z * b.z + b.w * b.w;
      float sab = a.x * b.x + a.y * b.y + a.z * b.z + a.w * b.w;
#pragma unroll
      for (int m = 32; m >= 1; m >>= 1) {
        sa += __shfl_xor(sa, m);
        sb += __shfl_xor(sb, m);
        sab += __shfl_xor(sab, m);
      }
      float ra = 1.0f / fmaxf(sqrtf(sa), 1e-8f);
      float rb = 1.0f / fmaxf(sqrtf(sb), 1e-8f);
      ushort4 oa, ob;
      oa.x = f2bf(a.x * ra); oa.y = f2bf(a.y * ra); oa.z = f2bf(a.z * ra); oa.w = f2bf(a.w * ra);
      ob.x = f2bf(b.x * rb); ob.y = f2bf(b.y * rb); ob.z = f2bf(b.z * rb); ob.w = f2bf(b.w * rb);
      ((ushort4*)(znb + (size_t)i * DD))[lane] = oa;
      ((ushort4*)(znb + (size_t)(i + NB) * DD))[lane] = ob;
      posacc += sab * ra * rb;
    }
  }
  if (lane == 0) sred[wave] = posacc;
  __threadfence();
  cg::this_grid().sync();

  // ---------------- phase 2: psum commit; gsum blocks; symmetric den ------
  if (tid == 0) {
    float p = sred[0] + sred[1] + sred[2] + sred[3];
    unsafeAtomicAdd(&scal[0], p);
  }

  // 4 dedicated group-sum blocks (last 4): vsum[g][d] = sum_{i in g} zn[i][d]
  {
    int gsb = (int)blockIdx.x - ((int)gridDim.x - 4);
    if (gsb >= 0) {
      int r0 = gsb * (NB / 4);
      float acc[4] = {0.f, 0.f, 0.f, 0.f};
      int cnt[4] = {0, 0, 0, 0};
      for (int r = 0; r < NB / 4; ++r) {
        int row = r0 + r;
        int g = sf[row];
        float v = bf2f(znb[(size_t)row * DD + tid]);
#pragma unroll
        for (int q = 0; q < 4; ++q) {
          acc[q] += (g == q) ? v : 0.f;
          cnt[q] += (g == q) ? 1 : 0;
        }
      }
#pragma unroll
      for (int q = 0; q < 4; ++q) unsafeAtomicAdd(&vsum[q * DD + tid], acc[q]);
      if (tid == 0) {
#pragma unroll
        for (int q = 0; q < 4; ++q) unsafeAtomicAdd(&scal[2 + q], (float)cnt[q]);
      }
    }
  }

  // den tiles: dynamic stealing over 2080 symmetric tiles
  {
    const int u = lane >> 3;
    const int cp = (lane & 7) ^ u;
    const int ri = 2 * u + (cp >> 2);
    const int kelem = (cp & 3) * 8;
    const int slot = ((((lane & 1) << 2) | (lane >> 4)) ^ ((lane >> 1) & 7));
    const int fragoff = ((lane & 15) >> 1) * 128 + slot * 16;
    const int wrow = wave & 1, wcol = wave >> 1;
    const char* Abase = (const char*)&As[0][0];
    const char* Bbase = (const char*)&Bs[0][0];

    while (true) {
      if (tid == 0) sh_t = atomicAdd(counter, 1u);
      __syncthreads();
      unsigned t = sh_t;
      if (t >= NTILES) break;
      unsigned tr = 0;
      while (t >= 64u - tr) { t -= 64u - tr; ++tr; }
      unsigned tc = tr + t;
      const bool diag = (tr == tc);
      const size_t rowbase = (size_t)tr * 128, colbase = (size_t)tc * 128;

      f32x4 zero = {0.f, 0.f, 0.f, 0.f};
      f32x4 acc[4][4];
#pragma unroll
      for (int i = 0; i < 4; ++i)
#pragma unroll
        for (int j = 0; j < 4; ++j) acc[i][j] = zero;

      auto stage = [&](int kt, int buf) {
#pragma unroll
        for (int j = 0; j < 2; ++j) {
          int is = wave * 2 + j;
          const unsigned short* gpa = znb + (rowbase + is * 16 + ri) * DD + kt * 32 + kelem;
          __builtin_amdgcn_global_load_lds((gvoid_t*)gpa, (lvoid_t*)&As[buf][is * 512], 16, 0, 0);
          if (!diag) {
            const unsigned short* gpb = znb + (colbase + is * 16 + ri) * DD + kt * 32 + kelem;
            __builtin_amdgcn_global_load_lds((gvoid_t*)gpb, (lvoid_t*)&Bs[buf][is * 512], 16, 0, 0);
          }
        }
      };

      stage(0, 0);
      __syncthreads();
      const char* Bb = diag ? Abase : Bbase;
#pragma unroll
      for (int kt = 0; kt < 8; ++kt) {
        if (kt < 7) stage(kt + 1, (kt + 1) & 1);
        const int buf = kt & 1;
        short8 af[4], bfr[4];
#pragma unroll
        for (int mi = 0; mi < 4; ++mi)
          af[mi] = *(const short8*)(Abase + buf * 8192 + wrow * 4096 + mi * 1024 + fragoff);
#pragma unroll
        for (int ni = 0; ni < 4; ++ni)
          bfr[ni] = *(const short8*)(Bb + buf * 8192 + wcol * 4096 + ni * 1024 + fragoff);
#pragma unroll
        for (int mi = 0; mi < 4; ++mi)
#pragma unroll
          for (int ni = 0; ni < 4; ++ni)
            acc[mi][ni] = __builtin_amdgcn_mfma_f32_16x16x32_bf16(af[mi], bfr[ni], acc[mi][ni], 0, 0, 0);
        __syncthreads();
      }

      // epilogue: e = exp(2S); row sums always; col sums for off-diag tiles.
      // C layout: col = lane&15, row = (lane>>4)*4 + reg.
      float rsum[4][4];
      float csum[4] = {0.f, 0.f, 0.f, 0.f};
#pragma unroll
      for (int mi = 0; mi < 4; ++mi)
#pragma unroll
        for (int r = 0; r < 4; ++r) rsum[mi][r] = 0.f;
#pragma unroll
      for (int mi = 0; mi < 4; ++mi)
#pragma unroll
        for (int ni = 0; ni < 4; ++ni)
#pragma unroll
          for (int r = 0; r < 4; ++r) {
            float e = __expf(2.0f * acc[mi][ni][r]);
            rsum[mi][r] += e;
            csum[ni] += e;
          }
#pragma unroll
      for (int m = 1; m < 16; m <<= 1)
#pragma unroll
        for (int mi = 0; mi < 4; ++mi)
#pragma unroll
          for (int r = 0; r < 4; ++r) rsum[mi][r] += __shfl_xor(rsum[mi][r], m);
      if ((lane & 15) == 0) {
        int h = lane >> 4;
#pragma unroll
        for (int mi = 0; mi < 4; ++mi)
#pragma unroll
          for (int r = 0; r < 4; ++r)
            unsafeAtomicAdd(&den[rowbase + wrow * 64 + mi * 16 + h * 4 + r], rsum[mi][r]);
      }
      if (!diag) {
#pragma unroll
        for (int m = 16; m < 64; m <<= 1)
#pragma unroll
          for (int ni = 0; ni < 4; ++ni) csum[ni] += __shfl_xor(csum[ni], m);
        if (lane < 16) {
#pragma unroll
          for (int ni = 0; ni < 4; ++ni)
            unsafeAtomicAdd(&den[colbase + wcol * 64 + ni * 16 + lane], csum[ni]);
        }
      }
    }
  }
  __threadfence();
  cg::this_grid().sync();

  // ---------------- phase 3a: log-reduce den; block0 computes gsq ---------
  float gsqr[4] = {0.f, 0.f, 0.f, 0.f};
  {
    const float e2 = __expf(2.0f);
    float lpart = 0.f;
    int idx = blockIdx.x * 256 + tid;
    if (idx < TWOB) lpart = logf(den[idx] - e2);
#pragma unroll
    for (int m = 32; m >= 1; m >>= 1) lpart += __shfl_xor(lpart, m);
    if (lane == 0) sred[wave] = lpart;
    __syncthreads();
    if (tid == 0) unsafeAtomicAdd(&scal[1], sred[0] + sred[1] + sred[2] + sred[3]);
    __syncthreads();
    if (blockIdx.x == 0) {
#pragma unroll
      for (int g = 0; g < 4; ++g) {
        float v = vsum[g * DD + tid];
        float p = v * v;
#pragma unroll
        for (int m = 32; m >= 1; m >>= 1) p += __shfl_xor(p, m);
        if (lane == 0) sred[wave] = p;
        __syncthreads();
        if (tid == 0) gsqr[g] = sred[0] + sred[1] + sred[2] + sred[3];
        __syncthreads();
      }
    }
  }
  __threadfence();
  cg::this_grid().sync();

  // ---------------- phase 3b: finalize ------------------------------------
  if (blockIdx.x == 0 && tid == 0) {
    float psumv = scal[0];
    float lsumv = scal[1];
    float contrastive = (lsumv - 4.0f * psumv) / (float)TWOB;
    float fsum = 0.f;
    int uniq = 0;
#pragma unroll
    for (int q = 0; q < 4; ++q) {
      float c = scal[2 + q];
      if (c > 0.5f) uniq++;
      if (c > 1.5f) fsum += gsqr[q] / (c * (c - 1.0f));
    }
    out[0] = contrastive + 0.1f * (fsum / (uniq > 0 ? (float)uniq : 1.0f));
  }
}

// ======================= fallback (non-cooperative) path =====================
__global__ __launch_bounds__(256) void norm_kernel(const float* __restrict__ zi,
                                                   const float* __restrict__ zj,
                                                   unsigned short* __restrict__ znb) {
  int wave = threadIdx.x >> 6, lane = threadIdx.x & 63;
  int row = blockIdx.x * 4 + wave;
  const float* src = (row < NB) ? (zi + (size_t)row * DD) : (zj + (size_t)(row - NB) * DD);
  float4 v = ((const float4*)src)[lane];
  float ss = v.x * v.x + v.y * v.y + v.z * v.z + v.w * v.w;
#pragma unroll
  for (int m = 32; m >= 1; m >>= 1) ss += __shfl_xor(ss, m);
  float s = 1.0f / fmaxf(sqrtf(ss), 1e-8f);
  ushort4 o;
  o.x = f2bf(v.x * s); o.y = f2bf(v.y * s); o.z = f2bf(v.z * s); o.w = f2bf(v.w * s);
  ((ushort4*)(znb + (size_t)row * DD))[lane] = o;
}

__global__ __launch_bounds__(256) void pos_kernel(const unsigned short* __restrict__ znb,
                                                  float* __restrict__ pos) {
  int wave = threadIdx.x >> 6, lane = threadIdx.x & 63;
  int row = blockIdx.x * 4 + wave;
  ushort4 a = ((const ushort4*)(znb + (size_t)row * DD))[lane];
  ushort4 b = ((const ushort4*)(znb + (size_t)(row + NB) * DD))[lane];
  float d = bf2f(a.x) * bf2f(b.x) + bf2f(a.y) * bf2f(b.y) +
            bf2f(a.z) * bf2f(b.z) + bf2f(a.w) * bf2f(b.w);
#pragma unroll
  for (int m = 32; m >= 1; m >>= 1) d += __shfl_xor(d, m);
  if (lane == 0) pos[row] = d;
}

__global__ __launch_bounds__(256) void gsum_kernel(const unsigned short* __restrict__ znb,
                                                   const int* __restrict__ sf,
                                                   float* __restrict__ vsum) {
  int d = threadIdx.x;
  int base = blockIdx.x * 128;
  float acc[4] = {0.f, 0.f, 0.f, 0.f};
  for (int r = 0; r < 128; ++r) {
    int row = base + r;
    int g = sf[row];
    float v = bf2f(znb[(size_t)row * DD + d]);
#pragma unroll
    for (int q = 0; q < 4; ++q) acc[q] += (g == q) ? v : 0.0f;
  }
#pragma unroll
  for (int q = 0; q < 4; ++q) unsafeAtomicAdd(&vsum[q * DD + d], acc[q]);
}

__global__ __launch_bounds__(256, 3) void den_kernel(const unsigned short* __restrict__ znb,
                                                     float* __restrict__ den) {
  __shared__ __align__(16) unsigned short As[2][4096];
  __shared__ __align__(16) unsigned short Bs[2][4096];
  const int tid = threadIdx.x;
  const int lane = tid & 63, wave = tid >> 6;
  const size_t rowbase = blockIdx.x * 128, colbase = blockIdx.y * 128;
  const int u = lane >> 3;
  const int cp = (lane & 7) ^ u;
  const int ri = 2 * u + (cp >> 2);
  const int kelem = (cp & 3) * 8;
  const int slot = ((((lane & 1) << 2) | (lane >> 4)) ^ ((lane >> 1) & 7));
  const int fragoff = ((lane & 15) >> 1) * 128 + slot * 16;
  const int wrow = wave & 1, wcol = wave >> 1;
  f32x4 zero = {0.f, 0.f, 0.f, 0.f};
  f32x4 acc[4][4];
#pragma unroll
  for (int i = 0; i < 4; ++i)
#pragma unroll
    for (int j = 0; j < 4; ++j) acc[i][j] = zero;
  auto stage = [&](int kt, int buf) {
#pragma unroll
    for (int j = 0; j < 2; ++j) {
      int is = wave * 2 + j;
      const unsigned short* gpa = znb + (rowbase + is * 16 + ri) * DD + kt * 32 + kelem;
      __builtin_amdgcn_global_load_lds((gvoid_t*)gpa, (lvoid_t*)&As[buf][is * 512], 16, 0, 0);
      const unsigned short* gpb = znb + (colbase + is * 16 + ri) * DD + kt * 32 + kelem;
      __builtin_amdgcn_global_load_lds((gvoid_t*)gpb, (lvoid_t*)&Bs[buf][is * 512], 16, 0, 0);
    }
  };
  stage(0, 0);
  __syncthreads();
#pragma unroll
  for (int kt = 0; kt < 8; ++kt) {
    if (kt < 7) stage(kt + 1, (kt + 1) & 1);
    const int buf = kt & 1;
    short8 af[4], bfr[4];
#pragma unroll
    for (int mi = 0; mi < 4; ++mi)
      af[mi] = *(const short8*)((const char*)&As[buf][0] + wrow * 4096 + mi * 1024 + fragoff);
#pragma unroll
    for (int ni = 0; ni < 4; ++ni)
      bfr[ni] = *(const short8*)((const char*)&Bs[buf][0] + wcol * 4096 + ni * 1024 + fragoff);
#pragma unroll
    for (int mi = 0; mi < 4; ++mi)
#pragma unroll
      for (int ni = 0; ni < 4; ++ni)
        acc[mi][ni] = __builtin_amdgcn_mfma_f32_16x16x32_bf16(af[mi], bfr[ni], acc[mi][ni], 0, 0, 0);
    __syncthreads();
  }
  float rsum[4][4];
#pragma unroll
  for (int mi = 0; mi < 4; ++mi)
#pragma unroll
    for (int r = 0; r < 4; ++r) rsum[mi][r] = 0.f;
#pragma unroll
  for (int mi = 0; mi < 4; ++mi)
#pragma unroll
    for (int ni = 0; ni < 4; ++ni)
#pragma unroll
      for (int r = 0; r < 4; ++r) rsum[mi][r] += __expf(2.0f * acc[mi][ni][r]);
#pragma unroll
  for (int m = 1; m < 16; m <<= 1)
#pragma unroll
    for (int mi = 0; mi < 4; ++mi)
#pragma unroll
      for (int r = 0; r < 4; ++r) rsum[mi][r] += __shfl_xor(rsum[mi][r], m);
  if ((lane & 15) == 0) {
    int h = lane >> 4;
#pragma unroll
    for (int mi = 0; mi < 4; ++mi)
#pragma unroll
      for (int r = 0; r < 4; ++r)
        unsafeAtomicAdd(&den[rowbase + wrow * 64 + mi * 16 + h * 4 + r], rsum[mi][r]);
  }
}

__global__ __launch_bounds__(256) void final_kernel(const float* __restrict__ den,
                                                    const float* __restrict__ pos,
                                                    const float* __restrict__ vsum,
                                                    const int* __restrict__ sf,
                                                    float* __restrict__ out) {
  __shared__ float red[256];
  __shared__ float gsq[4];
  __shared__ int cnt[4];
  int tid = threadIdx.x;
  if (tid < 4) { gsq[tid] = 0.f; cnt[tid] = 0; }
  __syncthreads();
  int lc[4] = {0, 0, 0, 0};
  for (int r = tid; r < NB; r += 256) {
    int g = sf[r];
#pragma unroll
    for (int q = 0; q < 4; ++q) lc[q] += (g == q) ? 1 : 0;
  }
#pragma unroll
  for (int q = 0; q < 4; ++q) atomicAdd(&cnt[q], lc[q]);
  float ga[4] = {0.f, 0.f, 0.f, 0.f};
  for (int i = tid; i < 4 * DD; i += 256) {
    float v = vsum[i];
    int g = i >> 8;
#pragma unroll
    for (int q = 0; q < 4; ++q) ga[q] += (g == q) ? v * v : 0.f;
  }
#pragma unroll
  for (int q = 0; q < 4; ++q) atomicAdd(&gsq[q], ga[q]);
  const float e2 = __expf(2.0f);
  float ls = 0.f;
  for (int i = tid; i < TWOB; i += 256) ls += logf(den[i] - e2);
  float ps = 0.f;
  for (int i = tid; i < NB; i += 256) ps += pos[i];
  red[tid] = ls;
  __syncthreads();
  for (int s = 128; s > 0; s >>= 1) { if (tid < s) red[tid] += red[tid + s]; __syncthreads(); }
  float lstot = red[0];
  __syncthreads();
  red[tid] = ps;
  __syncthreads();
  for (int s = 128; s > 0; s >>= 1) { if (tid < s) red[tid] += red[tid + s]; __syncthreads(); }
  float pstot = red[0];
  __syncthreads();
  if (tid == 0) {
    float contrastive = (lstot - 4.0f * pstot) / (float)TWOB;
    float fsum = 0.f;
    int uniq = 0;
#pragma unroll
    for (int q = 0; q < 4; ++q) {
      float c = (float)cnt[q];
      if (cnt[q] > 0) uniq++;
      if (cnt[q] > 1) fsum += gsq[q] / (c * (c - 1.0f));
    }
    out[0] = contrastive + 0.1f * (fsum / (uniq > 0 ? (float)uniq : 1.0f));
  }
}

extern "C" void kernel_launch(void* const* d_in, const int* in_sizes, int n_in,
                              void* d_out, int out_size, void* d_ws, size_t ws_size,
                              hipStream_t stream) {
  const float* zi = (const float*)d_in[0];
  const float* zj = (const float*)d_in[1];
  const int* sf = (const int*)d_in[2];
  float* out = (float*)d_out;
  char* ws = (char*)d_ws;
  float* wsf = (float*)ws;                              // den/vsum/scal region
  unsigned short* znb = (unsigned short*)(ws + 65536);  // 8192x256 bf16 (4MB)

  int dev = 0;
  hipGetDevice(&dev);
  int coop = 0;
  hipDeviceGetAttribute(&coop, hipDeviceAttributeCooperativeLaunch, dev);
  int maxB = 0;
  hipOccupancyMaxActiveBlocksPerMultiprocessor(&maxB, fused_kernel, 256, 0);

  if (coop && maxB >= 1) {
    int blocksPerCU = maxB < 3 ? maxB : 3;
    int grid = blocksPerCU * 256;  // 256 CUs on MI355X
    void* args[] = {(void*)&zi, (void*)&zj, (void*)&sf, (void*)&wsf, (void*)&znb, (void*)&out};
    hipLaunchCooperativeKernel((const void*)fused_kernel, dim3(grid), dim3(256), args, 0, stream);
  } else {
    float* den = wsf;
    float* vsum = den + TWOB;
    float* pos = vsum + 1024;
    hipMemsetAsync(ws, 0, (TWOB + 1024) * sizeof(float), stream);
    hipLaunchKernelGGL(norm_kernel, dim3(TWOB / 4), dim3(256), 0, stream, zi, zj, znb);
    hipLaunchKernelGGL(gsum_kernel, dim3(32), dim3(256), 0, stream, znb, sf, vsum);
    hipLaunchKernelGGL(pos_kernel, dim3(NB / 4), dim3(256), 0, stream, znb, pos);
    hipLaunchKernelGGL(den_kernel, dim3(64, 64), dim3(256), 0, stream, znb, den);
    hipLaunchKernelGGL(final_kernel, dim3(1), dim3(256), 0, stream, den, pos, vsum, sf, out);
  }
}

// Round 3
// 241.752 us; speedup vs baseline: 1.4727x; 1.4727x over previous
//
#include <hip/hip_runtime.h>
#include <hip/hip_bf16.h>

typedef __attribute__((ext_vector_type(8))) short short8;
typedef __attribute__((ext_vector_type(4))) float f32x4;
typedef __attribute__((address_space(1))) const void gvoid_t;
typedef __attribute__((address_space(3))) void lvoid_t;

#define NB 4096   // B
#define DD 256    // D
#define TWOB 8192
#define NTILES 2080u  // 64*65/2 symmetric 128x128 tiles

__device__ __forceinline__ unsigned short f2bf(float f) {
  unsigned int u = __float_as_uint(f);
  u += 0x7fffu + ((u >> 16) & 1u);
  return (unsigned short)(u >> 16);
}
__device__ __forceinline__ float bf2f(unsigned short s) {
  return __uint_as_float(((unsigned int)s) << 16);
}

// Lightweight grid barrier: monotonic counter, one release-add per block,
// spin with s_sleep, agent-acquire fence on exit. cg::this_grid().sync()
// measured ~180us/sync on MI355X (R2 post-mortem) -- this replaces it.
__device__ __forceinline__ void gbar(unsigned* bar, unsigned target) {
  __syncthreads();
  if (threadIdx.x == 0) {
    __hip_atomic_fetch_add(bar, 1u, __ATOMIC_RELEASE, __HIP_MEMORY_SCOPE_AGENT);
    while (__hip_atomic_load(bar, __ATOMIC_ACQUIRE, __HIP_MEMORY_SCOPE_AGENT) < target)
      __builtin_amdgcn_s_sleep(8);
  }
  __syncthreads();
  __builtin_amdgcn_fence(__ATOMIC_ACQUIRE, "agent");
}

// ws float layout: [0..8191] den, [8192..9215] vsum, scal = wsf+9216:
//   scal[0]=psum, scal[2..5]=counts, scal[8]=tile counter, scal[9]=barrier
__global__ __launch_bounds__(256, 3) void fused_kernel(const float* __restrict__ zi,
                                                       const float* __restrict__ zj,
                                                       const int* __restrict__ sf,
                                                       float* __restrict__ wsf,
                                                       unsigned short* __restrict__ znb,
                                                       float* __restrict__ out) {
  __shared__ __align__(16) unsigned short As[2][4096];  // 2 x 8KB
  __shared__ __align__(16) unsigned short Bs[2][4096];
  __shared__ float sred[32];
  __shared__ unsigned sh_t;

  float* den = wsf;
  float* vsum = wsf + 8192;
  float* scal = wsf + 9216;
  unsigned* tilecnt = (unsigned*)(scal + 8);
  unsigned* bar = (unsigned*)(scal + 9);

  const int tid = threadIdx.x;
  const int lane = tid & 63, wave = tid >> 6;
  const unsigned grid = gridDim.x;

  // ---------------- phase 1: normalize -> znb bf16; pos partials ----------
  float posacc = 0.f;
  {
    int gw = blockIdx.x * 4 + wave;
    int nw = grid * 4;
    for (int i = gw; i < NB; i += nw) {
      float4 a = ((const float4*)(zi + (size_t)i * DD))[lane];
      float4 b = ((const float4*)(zj + (size_t)i * DD))[lane];
      float sa = a.x * a.x + a.y * a.y + a.z * a.z + a.w * a.w;
      float sb = b.x * b.x + b.y * b.y + b.z * b.z + b.w * b.w;
      float sab = a.x * b.x + a.y * b.y + a.z * b.z + a.w * b.w;
#pragma unroll
      for (int m = 32; m >= 1; m >>= 1) {
        sa += __shfl_xor(sa, m);
        sb += __shfl_xor(sb, m);
        sab += __shfl_xor(sab, m);
      }
      float ra = 1.0f / fmaxf(sqrtf(sa), 1e-8f);
      float rb = 1.0f / fmaxf(sqrtf(sb), 1e-8f);
      ushort4 oa, ob;
      oa.x = f2bf(a.x * ra); oa.y = f2bf(a.y * ra); oa.z = f2bf(a.z * ra); oa.w = f2bf(a.w * ra);
      ob.x = f2bf(b.x * rb); ob.y = f2bf(b.y * rb); ob.z = f2bf(b.z * rb); ob.w = f2bf(b.w * rb);
      ((ushort4*)(znb + (size_t)i * DD))[lane] = oa;
      ((ushort4*)(znb + (size_t)(i + NB) * DD))[lane] = ob;
      posacc += sab * ra * rb;
    }
  }
  if (lane == 0) sred[wave] = posacc;
  __syncthreads();
  if (tid == 0) unsafeAtomicAdd(&scal[0], sred[0] + sred[1] + sred[2] + sred[3]);

  gbar(bar, grid);  // znb complete

  // ---------------- phase 2a: 16 gsum blocks (then they join stealing) ----
  {
    int gsb = (int)blockIdx.x - ((int)grid - 16);
    if (gsb >= 0) {
      int r0 = gsb * (NB / 16);
      float acc[4] = {0.f, 0.f, 0.f, 0.f};
      int cnt[4] = {0, 0, 0, 0};
      for (int r = 0; r < NB / 16; ++r) {
        int row = r0 + r;
        int g = sf[row];
        float v = bf2f(znb[(size_t)row * DD + tid]);
#pragma unroll
        for (int q = 0; q < 4; ++q) {
          acc[q] += (g == q) ? v : 0.f;
          cnt[q] += (g == q) ? 1 : 0;
        }
      }
#pragma unroll
      for (int q = 0; q < 4; ++q) unsafeAtomicAdd(&vsum[q * DD + tid], acc[q]);
      if (tid == 0) {
#pragma unroll
        for (int q = 0; q < 4; ++q) unsafeAtomicAdd(&scal[2 + q], (float)cnt[q]);
      }
    }
  }

  // ---------------- phase 2b: symmetric den tiles (dynamic stealing) ------
  {
    const int u = lane >> 3;
    const int cp = (lane & 7) ^ u;
    const int ri = 2 * u + (cp >> 2);
    const int kelem = (cp & 3) * 8;
    const int slot = ((((lane & 1) << 2) | (lane >> 4)) ^ ((lane >> 1) & 7));
    const int fragoff = ((lane & 15) >> 1) * 128 + slot * 16;
    const int wrow = wave & 1, wcol = wave >> 1;
    const char* Abase = (const char*)&As[0][0];
    const char* Bbase = (const char*)&Bs[0][0];

    while (true) {
      if (tid == 0) sh_t = atomicAdd(tilecnt, 1u);
      __syncthreads();
      unsigned t = sh_t;
      if (t >= NTILES) break;
      unsigned tr = 0;
      while (t >= 64u - tr) { t -= 64u - tr; ++tr; }
      unsigned tc = tr + t;
      const bool diag = (tr == tc);
      const size_t rowbase = (size_t)tr * 128, colbase = (size_t)tc * 128;

      f32x4 zero = {0.f, 0.f, 0.f, 0.f};
      f32x4 acc[4][4];
#pragma unroll
      for (int i = 0; i < 4; ++i)
#pragma unroll
        for (int j = 0; j < 4; ++j) acc[i][j] = zero;

      auto stage = [&](int kt, int buf) {
#pragma unroll
        for (int j = 0; j < 2; ++j) {
          int is = wave * 2 + j;
          const unsigned short* gpa = znb + (rowbase + is * 16 + ri) * DD + kt * 32 + kelem;
          __builtin_amdgcn_global_load_lds((gvoid_t*)gpa, (lvoid_t*)&As[buf][is * 512], 16, 0, 0);
          if (!diag) {
            const unsigned short* gpb = znb + (colbase + is * 16 + ri) * DD + kt * 32 + kelem;
            __builtin_amdgcn_global_load_lds((gvoid_t*)gpb, (lvoid_t*)&Bs[buf][is * 512], 16, 0, 0);
          }
        }
      };

      stage(0, 0);
      __syncthreads();
      const char* Bb = diag ? Abase : Bbase;
#pragma unroll
      for (int kt = 0; kt < 8; ++kt) {
        if (kt < 7) stage(kt + 1, (kt + 1) & 1);
        const int buf = kt & 1;
        short8 af[4], bfr[4];
#pragma unroll
        for (int mi = 0; mi < 4; ++mi)
          af[mi] = *(const short8*)(Abase + buf * 8192 + wrow * 4096 + mi * 1024 + fragoff);
#pragma unroll
        for (int ni = 0; ni < 4; ++ni)
          bfr[ni] = *(const short8*)(Bb + buf * 8192 + wcol * 4096 + ni * 1024 + fragoff);
#pragma unroll
        for (int mi = 0; mi < 4; ++mi)
#pragma unroll
          for (int ni = 0; ni < 4; ++ni)
            acc[mi][ni] = __builtin_amdgcn_mfma_f32_16x16x32_bf16(af[mi], bfr[ni], acc[mi][ni], 0, 0, 0);
        __syncthreads();
      }

      // epilogue: e = exp(2S); row sums always; col sums for off-diag tiles.
      // C layout: col = lane&15, row = (lane>>4)*4 + reg.
      float rsum[4][4];
      float csum[4] = {0.f, 0.f, 0.f, 0.f};
#pragma unroll
      for (int mi = 0; mi < 4; ++mi)
#pragma unroll
        for (int r = 0; r < 4; ++r) rsum[mi][r] = 0.f;
#pragma unroll
      for (int mi = 0; mi < 4; ++mi)
#pragma unroll
        for (int ni = 0; ni < 4; ++ni)
#pragma unroll
          for (int r = 0; r < 4; ++r) {
            float e = __expf(2.0f * acc[mi][ni][r]);
            rsum[mi][r] += e;
            csum[ni] += e;
          }
#pragma unroll
      for (int m = 1; m < 16; m <<= 1)
#pragma unroll
        for (int mi = 0; mi < 4; ++mi)
#pragma unroll
          for (int r = 0; r < 4; ++r) rsum[mi][r] += __shfl_xor(rsum[mi][r], m);
      if ((lane & 15) == 0) {
        int h = lane >> 4;
#pragma unroll
        for (int mi = 0; mi < 4; ++mi)
#pragma unroll
          for (int r = 0; r < 4; ++r)
            unsafeAtomicAdd(&den[rowbase + wrow * 64 + mi * 16 + h * 4 + r], rsum[mi][r]);
      }
      if (!diag) {
#pragma unroll
        for (int m = 16; m < 64; m <<= 1)
#pragma unroll
          for (int ni = 0; ni < 4; ++ni) csum[ni] += __shfl_xor(csum[ni], m);
        if (lane < 16) {
#pragma unroll
          for (int ni = 0; ni < 4; ++ni)
            unsafeAtomicAdd(&den[colbase + wcol * 64 + ni * 16 + lane], csum[ni]);
        }
      }
    }
  }

  gbar(bar, 2u * grid);  // den/vsum/scal complete

  // ---------------- phase 3: block-0 tail --------------------------------
  if (blockIdx.x == 0) {
    float p[4];
#pragma unroll
    for (int g = 0; g < 4; ++g) {
      float v = vsum[g * DD + tid];
      p[g] = v * v;
#pragma unroll
      for (int m = 32; m >= 1; m >>= 1) p[g] += __shfl_xor(p[g], m);
    }
    if (lane == 0) {
#pragma unroll
      for (int g = 0; g < 4; ++g) sred[wave * 4 + g] = p[g];
    }
    const float e2 = __expf(2.0f);
    float ls = 0.f;
    for (int i = tid; i < TWOB; i += 256) ls += __logf(den[i] - e2);
#pragma unroll
    for (int m = 32; m >= 1; m >>= 1) ls += __shfl_xor(ls, m);
    if (lane == 0) sred[16 + wave] = ls;
    __syncthreads();
    if (tid == 0) {
      float lsum = sred[16] + sred[17] + sred[18] + sred[19];
      float psum = scal[0];
      float contrastive = (lsum - 4.0f * psum) / (float)TWOB;
      float fsum = 0.f;
      int uniq = 0;
#pragma unroll
      for (int q = 0; q < 4; ++q) {
        float gsq = sred[q] + sred[4 + q] + sred[8 + q] + sred[12 + q];
        float c = scal[2 + q];
        if (c > 0.5f) uniq++;
        if (c > 1.5f) fsum += gsq / (c * (c - 1.0f));
      }
      out[0] = contrastive + 0.1f * (fsum / (uniq > 0 ? (float)uniq : 1.0f));
    }
  }
}

// ======================= fallback (non-cooperative) path =====================
__global__ __launch_bounds__(256) void norm_kernel(const float* __restrict__ zi,
                                                   const float* __restrict__ zj,
                                                   unsigned short* __restrict__ znb) {
  int wave = threadIdx.x >> 6, lane = threadIdx.x & 63;
  int row = blockIdx.x * 4 + wave;
  const float* src = (row < NB) ? (zi + (size_t)row * DD) : (zj + (size_t)(row - NB) * DD);
  float4 v = ((const float4*)src)[lane];
  float ss = v.x * v.x + v.y * v.y + v.z * v.z + v.w * v.w;
#pragma unroll
  for (int m = 32; m >= 1; m >>= 1) ss += __shfl_xor(ss, m);
  float s = 1.0f / fmaxf(sqrtf(ss), 1e-8f);
  ushort4 o;
  o.x = f2bf(v.x * s); o.y = f2bf(v.y * s); o.z = f2bf(v.z * s); o.w = f2bf(v.w * s);
  ((ushort4*)(znb + (size_t)row * DD))[lane] = o;
}

__global__ __launch_bounds__(256) void pos_kernel(const unsigned short* __restrict__ znb,
                                                  float* __restrict__ pos) {
  int wave = threadIdx.x >> 6, lane = threadIdx.x & 63;
  int row = blockIdx.x * 4 + wave;
  ushort4 a = ((const ushort4*)(znb + (size_t)row * DD))[lane];
  ushort4 b = ((const ushort4*)(znb + (size_t)(row + NB) * DD))[lane];
  float d = bf2f(a.x) * bf2f(b.x) + bf2f(a.y) * bf2f(b.y) +
            bf2f(a.z) * bf2f(b.z) + bf2f(a.w) * bf2f(b.w);
#pragma unroll
  for (int m = 32; m >= 1; m >>= 1) d += __shfl_xor(d, m);
  if (lane == 0) pos[row] = d;
}

__global__ __launch_bounds__(256) void gsum_kernel(const unsigned short* __restrict__ znb,
                                                   const int* __restrict__ sf,
                                                   float* __restrict__ vsum) {
  int d = threadIdx.x;
  int base = blockIdx.x * 128;
  float acc[4] = {0.f, 0.f, 0.f, 0.f};
  for (int r = 0; r < 128; ++r) {
    int row = base + r;
    int g = sf[row];
    float v = bf2f(znb[(size_t)row * DD + d]);
#pragma unroll
    for (int q = 0; q < 4; ++q) acc[q] += (g == q) ? v : 0.0f;
  }
#pragma unroll
  for (int q = 0; q < 4; ++q) unsafeAtomicAdd(&vsum[q * DD + d], acc[q]);
}

__global__ __launch_bounds__(256, 3) void den_kernel(const unsigned short* __restrict__ znb,
                                                     float* __restrict__ den) {
  __shared__ __align__(16) unsigned short As[2][4096];
  __shared__ __align__(16) unsigned short Bs[2][4096];
  const int tid = threadIdx.x;
  const int lane = tid & 63, wave = tid >> 6;
  const size_t rowbase = blockIdx.x * 128, colbase = blockIdx.y * 128;
  const int u = lane >> 3;
  const int cp = (lane & 7) ^ u;
  const int ri = 2 * u + (cp >> 2);
  const int kelem = (cp & 3) * 8;
  const int slot = ((((lane & 1) << 2) | (lane >> 4)) ^ ((lane >> 1) & 7));
  const int fragoff = ((lane & 15) >> 1) * 128 + slot * 16;
  const int wrow = wave & 1, wcol = wave >> 1;
  f32x4 zero = {0.f, 0.f, 0.f, 0.f};
  f32x4 acc[4][4];
#pragma unroll
  for (int i = 0; i < 4; ++i)
#pragma unroll
    for (int j = 0; j < 4; ++j) acc[i][j] = zero;
  auto stage = [&](int kt, int buf) {
#pragma unroll
    for (int j = 0; j < 2; ++j) {
      int is = wave * 2 + j;
      const unsigned short* gpa = znb + (rowbase + is * 16 + ri) * DD + kt * 32 + kelem;
      __builtin_amdgcn_global_load_lds((gvoid_t*)gpa, (lvoid_t*)&As[buf][is * 512], 16, 0, 0);
      const unsigned short* gpb = znb + (colbase + is * 16 + ri) * DD + kt * 32 + kelem;
      __builtin_amdgcn_global_load_lds((gvoid_t*)gpb, (lvoid_t*)&Bs[buf][is * 512], 16, 0, 0);
    }
  };
  stage(0, 0);
  __syncthreads();
#pragma unroll
  for (int kt = 0; kt < 8; ++kt) {
    if (kt < 7) stage(kt + 1, (kt + 1) & 1);
    const int buf = kt & 1;
    short8 af[4], bfr[4];
#pragma unroll
    for (int mi = 0; mi < 4; ++mi)
      af[mi] = *(const short8*)((const char*)&As[buf][0] + wrow * 4096 + mi * 1024 + fragoff);
#pragma unroll
    for (int ni = 0; ni < 4; ++ni)
      bfr[ni] = *(const short8*)((const char*)&Bs[buf][0] + wcol * 4096 + ni * 1024 + fragoff);
#pragma unroll
    for (int mi = 0; mi < 4; ++mi)
#pragma unroll
      for (int ni = 0; ni < 4; ++ni)
        acc[mi][ni] = __builtin_amdgcn_mfma_f32_16x16x32_bf16(af[mi], bfr[ni], acc[mi][ni], 0, 0, 0);
    __syncthreads();
  }
  float rsum[4][4];
#pragma unroll
  for (int mi = 0; mi < 4; ++mi)
#pragma unroll
    for (int r = 0; r < 4; ++r) rsum[mi][r] = 0.f;
#pragma unroll
  for (int mi = 0; mi < 4; ++mi)
#pragma unroll
    for (int ni = 0; ni < 4; ++ni)
#pragma unroll
      for (int r = 0; r < 4; ++r) rsum[mi][r] += __expf(2.0f * acc[mi][ni][r]);
#pragma unroll
  for (int m = 1; m < 16; m <<= 1)
#pragma unroll
    for (int mi = 0; mi < 4; ++mi)
#pragma unroll
      for (int r = 0; r < 4; ++r) rsum[mi][r] += __shfl_xor(rsum[mi][r], m);
  if ((lane & 15) == 0) {
    int h = lane >> 4;
#pragma unroll
    for (int mi = 0; mi < 4; ++mi)
#pragma unroll
      for (int r = 0; r < 4; ++r)
        unsafeAtomicAdd(&den[rowbase + wrow * 64 + mi * 16 + h * 4 + r], rsum[mi][r]);
  }
}

__global__ __launch_bounds__(256) void final_kernel(const float* __restrict__ den,
                                                    const float* __restrict__ pos,
                                                    const float* __restrict__ vsum,
                                                    const int* __restrict__ sf,
                                                    float* __restrict__ out) {
  __shared__ float red[256];
  __shared__ float gsq[4];
  __shared__ int cnt[4];
  int tid = threadIdx.x;
  if (tid < 4) { gsq[tid] = 0.f; cnt[tid] = 0; }
  __syncthreads();
  int lc[4] = {0, 0, 0, 0};
  for (int r = tid; r < NB; r += 256) {
    int g = sf[r];
#pragma unroll
    for (int q = 0; q < 4; ++q) lc[q] += (g == q) ? 1 : 0;
  }
#pragma unroll
  for (int q = 0; q < 4; ++q) atomicAdd(&cnt[q], lc[q]);
  float ga[4] = {0.f, 0.f, 0.f, 0.f};
  for (int i = tid; i < 4 * DD; i += 256) {
    float v = vsum[i];
    int g = i >> 8;
#pragma unroll
    for (int q = 0; q < 4; ++q) ga[q] += (g == q) ? v * v : 0.f;
  }
#pragma unroll
  for (int q = 0; q < 4; ++q) atomicAdd(&gsq[q], ga[q]);
  const float e2 = __expf(2.0f);
  float ls = 0.f;
  for (int i = tid; i < TWOB; i += 256) ls += logf(den[i] - e2);
  float ps = 0.f;
  for (int i = tid; i < NB; i += 256) ps += pos[i];
  red[tid] = ls;
  __syncthreads();
  for (int s = 128; s > 0; s >>= 1) { if (tid < s) red[tid] += red[tid + s]; __syncthreads(); }
  float lstot = red[0];
  __syncthreads();
  red[tid] = ps;
  __syncthreads();
  for (int s = 128; s > 0; s >>= 1) { if (tid < s) red[tid] += red[tid + s]; __syncthreads(); }
  float pstot = red[0];
  __syncthreads();
  if (tid == 0) {
    float contrastive = (lstot - 4.0f * pstot) / (float)TWOB;
    float fsum = 0.f;
    int uniq = 0;
#pragma unroll
    for (int q = 0; q < 4; ++q) {
      float c = (float)cnt[q];
      if (cnt[q] > 0) uniq++;
      if (cnt[q] > 1) fsum += gsq[q] / (c * (c - 1.0f));
    }
    out[0] = contrastive + 0.1f * (fsum / (uniq > 0 ? (float)uniq : 1.0f));
  }
}

extern "C" void kernel_launch(void* const* d_in, const int* in_sizes, int n_in,
                              void* d_out, int out_size, void* d_ws, size_t ws_size,
                              hipStream_t stream) {
  const float* zi = (const float*)d_in[0];
  const float* zj = (const float*)d_in[1];
  const int* sf = (const int*)d_in[2];
  float* out = (float*)d_out;
  char* ws = (char*)d_ws;
  float* wsf = (float*)ws;                              // den/vsum/scal region
  unsigned short* znb = (unsigned short*)(ws + 65536);  // 8192x256 bf16 (4MB)

  int dev = 0;
  hipGetDevice(&dev);
  int coop = 0, numCU = 256;
  hipDeviceGetAttribute(&coop, hipDeviceAttributeCooperativeLaunch, dev);
  hipDeviceGetAttribute(&numCU, hipDeviceAttributeMultiprocessorCount, dev);
  int maxB = 0;
  hipOccupancyMaxActiveBlocksPerMultiprocessor(&maxB, fused_kernel, 256, 0);

  if (coop && maxB >= 1) {
    int blocksPerCU = maxB < 3 ? maxB : 3;
    int grid = blocksPerCU * numCU;
    // zero den/vsum/scal + tile & barrier counters (40KB) before the kernel
    hipMemsetAsync(ws, 0, 40960, stream);
    void* args[] = {(void*)&zi, (void*)&zj, (void*)&sf, (void*)&wsf, (void*)&znb, (void*)&out};
    hipLaunchCooperativeKernel((const void*)fused_kernel, dim3(grid), dim3(256), args, 0, stream);
  } else {
    float* den = wsf;
    float* vsum = den + TWOB;
    float* pos = vsum + 1024;
    hipMemsetAsync(ws, 0, (TWOB + 1024) * sizeof(float), stream);
    hipLaunchKernelGGL(norm_kernel, dim3(TWOB / 4), dim3(256), 0, stream, zi, zj, znb);
    hipLaunchKernelGGL(gsum_kernel, dim3(32), dim3(256), 0, stream, znb, sf, vsum);
    hipLaunchKernelGGL(pos_kernel, dim3(NB / 4), dim3(256), 0, stream, znb, pos);
    hipLaunchKernelGGL(den_kernel, dim3(64, 64), dim3(256), 0, stream, znb, den);
    hipLaunchKernelGGL(final_kernel, dim3(1), dim3(256), 0, stream, den, pos, vsum, sf, out);
  }
}

// Round 4
// 154.066 us; speedup vs baseline: 2.3109x; 1.5691x over previous
//
#include <hip/hip_runtime.h>
#include <hip/hip_bf16.h>

typedef __attribute__((ext_vector_type(8))) short short8;
typedef __attribute__((ext_vector_type(4))) float f32x4;
typedef __attribute__((address_space(1))) const void gvoid_t;
typedef __attribute__((address_space(3))) void lvoid_t;

#define NB 4096   // B
#define DD 256    // D
#define TWOB 8192
#define NTILES 2080u   // 64*65/2 symmetric 128x128 tiles
#define GRID_B 768     // 3 blocks/CU x 256 CUs; regular launch, stealing is robust anyway

__device__ __forceinline__ unsigned short f2bf(float f) {
  unsigned int u = __float_as_uint(f);
  u += 0x7fffu + ((u >> 16) & 1u);
  return (unsigned short)(u >> 16);
}
__device__ __forceinline__ float bf2f(unsigned short s) {
  return __uint_as_float(((unsigned int)s) << 16);
}

// ws float layout: [0..8191] den, [8192..9215] vsum, scal = wsf+9216:
//   scal[0]=psum, scal[2..5]=counts, scal[8]=tile counter, scal[9]=done counter
// All zeroed by a hipMemsetAsync graph node before kernel A.

// ---------------- kernel A: normalize -> znb bf16; pos -------------------
// One wave per row pair (zi[i], zj[i]). 4096 waves = 1024 blocks.
__global__ __launch_bounds__(256) void norm_pos_kernel(const float* __restrict__ zi,
                                                       const float* __restrict__ zj,
                                                       float* __restrict__ wsf,
                                                       unsigned short* __restrict__ znb) {
  __shared__ float sred[4];
  float* scal = wsf + 9216;
  const int lane = threadIdx.x & 63, wave = threadIdx.x >> 6;
  const int i = blockIdx.x * 4 + wave;

  float4 a = ((const float4*)(zi + (size_t)i * DD))[lane];
  float4 b = ((const float4*)(zj + (size_t)i * DD))[lane];
  float sa = a.x * a.x + a.y * a.y + a.z * a.z + a.w * a.w;
  float sb = b.x * b.x + b.y * b.y + b.z * b.z + b.w * b.w;
  float sab = a.x * b.x + a.y * b.y + a.z * b.z + a.w * b.w;
#pragma unroll
  for (int m = 32; m >= 1; m >>= 1) {
    sa += __shfl_xor(sa, m);
    sb += __shfl_xor(sb, m);
    sab += __shfl_xor(sab, m);
  }
  float ra = 1.0f / fmaxf(sqrtf(sa), 1e-8f);
  float rb = 1.0f / fmaxf(sqrtf(sb), 1e-8f);
  ushort4 oa, ob;
  oa.x = f2bf(a.x * ra); oa.y = f2bf(a.y * ra); oa.z = f2bf(a.z * ra); oa.w = f2bf(a.w * ra);
  ob.x = f2bf(b.x * rb); ob.y = f2bf(b.y * rb); ob.z = f2bf(b.z * rb); ob.w = f2bf(b.w * rb);
  ((ushort4*)(znb + (size_t)i * DD))[lane] = oa;
  ((ushort4*)(znb + (size_t)(i + NB) * DD))[lane] = ob;

  if (lane == 0) sred[wave] = sab * ra * rb;
  __syncthreads();
  if (threadIdx.x == 0)
    unsafeAtomicAdd(&scal[0], sred[0] + sred[1] + sred[2] + sred[3]);
}

// ---------------- kernel B: gsum role + symmetric den tiles + tail --------
__global__ __launch_bounds__(256, 3) void den_tail_kernel(const int* __restrict__ sf,
                                                          float* __restrict__ wsf,
                                                          const unsigned short* __restrict__ znb,
                                                          float* __restrict__ out) {
  __shared__ __align__(16) unsigned short As[2][4096];  // 2 x 8KB
  __shared__ __align__(16) unsigned short Bs[2][4096];
  __shared__ float sred[32];
  __shared__ unsigned sh_t;
  __shared__ int sh_last;

  float* den = wsf;
  float* vsum = wsf + 8192;
  float* scal = wsf + 9216;
  unsigned* tilecnt = (unsigned*)(scal + 8);
  unsigned* done = (unsigned*)(scal + 9);

  const int tid = threadIdx.x;
  const int lane = tid & 63, wave = tid >> 6;

  // ---- gsum role: blocks 0..15, 256 rows each (znb valid: kernel boundary)
  if (blockIdx.x < 16) {
    const int r0 = blockIdx.x * 256;
    // counts: one row per thread, ballot per wave
    {
      int g = sf[r0 + tid];
#pragma unroll
      for (int q = 0; q < 4; ++q) {
        unsigned long long m = __ballot(g == q);
        if (lane == 0) unsafeAtomicAdd(&scal[2 + q], (float)__popcll(m));
      }
    }
    // vsum: wave w handles rows [r0 + w*64, +64); lane covers d = lane*4..+3
    float acc[4][4];
#pragma unroll
    for (int q = 0; q < 4; ++q)
#pragma unroll
      for (int e = 0; e < 4; ++e) acc[q][e] = 0.f;
    const int rw = r0 + wave * 64;
    for (int k = 0; k < 64; ++k) {
      int row = rw + k;
      int g = sf[row];
      ushort4 v = ((const ushort4*)(znb + (size_t)row * DD))[lane];
      float f0 = bf2f(v.x), f1 = bf2f(v.y), f2 = bf2f(v.z), f3 = bf2f(v.w);
#pragma unroll
      for (int q = 0; q < 4; ++q) {
        acc[q][0] += (g == q) ? f0 : 0.f;
        acc[q][1] += (g == q) ? f1 : 0.f;
        acc[q][2] += (g == q) ? f2 : 0.f;
        acc[q][3] += (g == q) ? f3 : 0.f;
      }
    }
#pragma unroll
    for (int q = 0; q < 4; ++q)
#pragma unroll
      for (int e = 0; e < 4; ++e)
        unsafeAtomicAdd(&vsum[q * DD + lane * 4 + e], acc[q][e]);
  }

  // ---- symmetric den tiles (dynamic stealing) ----------------------------
  {
    const int u = lane >> 3;
    const int cp = (lane & 7) ^ u;
    const int ri = 2 * u + (cp >> 2);
    const int kelem = (cp & 3) * 8;
    const int slot = ((((lane & 1) << 2) | (lane >> 4)) ^ ((lane >> 1) & 7));
    const int fragoff = ((lane & 15) >> 1) * 128 + slot * 16;
    const int wrow = wave & 1, wcol = wave >> 1;
    const char* Abase = (const char*)&As[0][0];
    const char* Bbase = (const char*)&Bs[0][0];

    while (true) {
      if (tid == 0) sh_t = atomicAdd(tilecnt, 1u);
      __syncthreads();
      unsigned t = sh_t;
      if (t >= NTILES) break;
      unsigned tr = 0;
      while (t >= 64u - tr) { t -= 64u - tr; ++tr; }
      unsigned tc = tr + t;
      const bool diag = (tr == tc);
      const size_t rowbase = (size_t)tr * 128, colbase = (size_t)tc * 128;

      f32x4 zero = {0.f, 0.f, 0.f, 0.f};
      f32x4 acc[4][4];
#pragma unroll
      for (int i = 0; i < 4; ++i)
#pragma unroll
        for (int j = 0; j < 4; ++j) acc[i][j] = zero;

      auto stage = [&](int kt, int buf) {
#pragma unroll
        for (int j = 0; j < 2; ++j) {
          int is = wave * 2 + j;
          const unsigned short* gpa = znb + (rowbase + is * 16 + ri) * DD + kt * 32 + kelem;
          __builtin_amdgcn_global_load_lds((gvoid_t*)gpa, (lvoid_t*)&As[buf][is * 512], 16, 0, 0);
          if (!diag) {
            const unsigned short* gpb = znb + (colbase + is * 16 + ri) * DD + kt * 32 + kelem;
            __builtin_amdgcn_global_load_lds((gvoid_t*)gpb, (lvoid_t*)&Bs[buf][is * 512], 16, 0, 0);
          }
        }
      };

      stage(0, 0);
      __syncthreads();
      const char* Bb = diag ? Abase : Bbase;
#pragma unroll
      for (int kt = 0; kt < 8; ++kt) {
        if (kt < 7) stage(kt + 1, (kt + 1) & 1);
        const int buf = kt & 1;
        short8 af[4], bfr[4];
#pragma unroll
        for (int mi = 0; mi < 4; ++mi)
          af[mi] = *(const short8*)(Abase + buf * 8192 + wrow * 4096 + mi * 1024 + fragoff);
#pragma unroll
        for (int ni = 0; ni < 4; ++ni)
          bfr[ni] = *(const short8*)(Bb + buf * 8192 + wcol * 4096 + ni * 1024 + fragoff);
#pragma unroll
        for (int mi = 0; mi < 4; ++mi)
#pragma unroll
          for (int ni = 0; ni < 4; ++ni)
            acc[mi][ni] = __builtin_amdgcn_mfma_f32_16x16x32_bf16(af[mi], bfr[ni], acc[mi][ni], 0, 0, 0);
        __syncthreads();
      }

      // epilogue: e = exp(2S); row sums always; col sums for off-diag tiles.
      // C layout: col = lane&15, row = (lane>>4)*4 + reg.
      float rsum[4][4];
      float csum[4] = {0.f, 0.f, 0.f, 0.f};
#pragma unroll
      for (int mi = 0; mi < 4; ++mi)
#pragma unroll
        for (int r = 0; r < 4; ++r) rsum[mi][r] = 0.f;
#pragma unroll
      for (int mi = 0; mi < 4; ++mi)
#pragma unroll
        for (int ni = 0; ni < 4; ++ni)
#pragma unroll
          for (int r = 0; r < 4; ++r) {
            float e = __expf(2.0f * acc[mi][ni][r]);
            rsum[mi][r] += e;
            csum[ni] += e;
          }
#pragma unroll
      for (int m = 1; m < 16; m <<= 1)
#pragma unroll
        for (int mi = 0; mi < 4; ++mi)
#pragma unroll
          for (int r = 0; r < 4; ++r) rsum[mi][r] += __shfl_xor(rsum[mi][r], m);
      if ((lane & 15) == 0) {
        int h = lane >> 4;
#pragma unroll
        for (int mi = 0; mi < 4; ++mi)
#pragma unroll
          for (int r = 0; r < 4; ++r)
            unsafeAtomicAdd(&den[rowbase + wrow * 64 + mi * 16 + h * 4 + r], rsum[mi][r]);
      }
      if (!diag) {
#pragma unroll
        for (int m = 16; m < 64; m <<= 1)
#pragma unroll
          for (int ni = 0; ni < 4; ++ni) csum[ni] += __shfl_xor(csum[ni], m);
        if (lane < 16) {
#pragma unroll
          for (int ni = 0; ni < 4; ++ni)
            unsafeAtomicAdd(&den[colbase + wcol * 64 + ni * 16 + lane], csum[ni]);
        }
      }
    }
  }

  // ---- arrive; LAST block computes the tail (no grid barrier, no polling)
  __syncthreads();
  if (tid == 0) {
    unsigned old = __hip_atomic_fetch_add(done, 1u, __ATOMIC_ACQ_REL, __HIP_MEMORY_SCOPE_AGENT);
    sh_last = (old == gridDim.x - 1) ? 1 : 0;
  }
  __syncthreads();
  if (!sh_last) return;
  __builtin_amdgcn_fence(__ATOMIC_ACQUIRE, "agent");

  // tail: log-reduce den, fairness from vsum, finalize
  const float e2 = __expf(2.0f);
  float ls = 0.f;
  for (int i = tid; i < TWOB; i += 256) ls += __logf(den[i] - e2);
#pragma unroll
  for (int m = 32; m >= 1; m >>= 1) ls += __shfl_xor(ls, m);
  if (lane == 0) sred[wave] = ls;
  float gp[4];
#pragma unroll
  for (int g = 0; g < 4; ++g) {
    float v = vsum[g * DD + tid];
    gp[g] = v * v;
#pragma unroll
    for (int m = 32; m >= 1; m >>= 1) gp[g] += __shfl_xor(gp[g], m);
  }
  if (lane == 0) {
#pragma unroll
    for (int g = 0; g < 4; ++g) sred[4 + wave * 4 + g] = gp[g];
  }
  __syncthreads();
  if (tid == 0) {
    float lsum = sred[0] + sred[1] + sred[2] + sred[3];
    float psum = scal[0];
    float contrastive = (lsum - 4.0f * psum) / (float)TWOB;
    float fsum = 0.f;
    int uniq = 0;
#pragma unroll
    for (int q = 0; q < 4; ++q) {
      float gsq = sred[4 + q] + sred[8 + q] + sred[12 + q] + sred[16 + q];
      float c = scal[2 + q];
      if (c > 0.5f) uniq++;
      if (c > 1.5f) fsum += gsq / (c * (c - 1.0f));
    }
    out[0] = contrastive + 0.1f * (fsum / (uniq > 0 ? (float)uniq : 1.0f));
  }
}

extern "C" void kernel_launch(void* const* d_in, const int* in_sizes, int n_in,
                              void* d_out, int out_size, void* d_ws, size_t ws_size,
                              hipStream_t stream) {
  const float* zi = (const float*)d_in[0];
  const float* zj = (const float*)d_in[1];
  const int* sf = (const int*)d_in[2];
  float* out = (float*)d_out;
  char* ws = (char*)d_ws;
  float* wsf = (float*)ws;                              // den/vsum/scal region
  unsigned short* znb = (unsigned short*)(ws + 65536);  // 8192x256 bf16 (4MB)

  // zero den + vsum + scal (incl. tile & done counters)
  hipMemsetAsync(ws, 0, 40960, stream);
  hipLaunchKernelGGL(norm_pos_kernel, dim3(1024), dim3(256), 0, stream, zi, zj, wsf, znb);
  hipLaunchKernelGGL(den_tail_kernel, dim3(GRID_B), dim3(256), 0, stream, sf, wsf, znb, out);
}

// Round 5
// 146.910 us; speedup vs baseline: 2.4234x; 1.0487x over previous
//
#include <hip/hip_runtime.h>
#include <hip/hip_bf16.h>

typedef __attribute__((ext_vector_type(8))) short short8;
typedef __attribute__((ext_vector_type(4))) float f32x4;
typedef __attribute__((address_space(1))) const void gvoid_t;
typedef __attribute__((address_space(3))) void lvoid_t;

#define NB 4096   // B
#define DD 256    // D
#define TWOB 8192
#define NTILES 2080u   // 64*65/2 symmetric 128x128 tiles
#define GSUM_BLOCKS 16
#define GRID_B (NTILES + GSUM_BLOCKS)

__device__ __forceinline__ unsigned short f2bf(float f) {
  unsigned int u = __float_as_uint(f);
  u += 0x7fffu + ((u >> 16) & 1u);
  return (unsigned short)(u >> 16);
}
__device__ __forceinline__ float bf2f(unsigned short s) {
  return __uint_as_float(((unsigned int)s) << 16);
}

// ws float layout: [0..8191] den, [8192..9215] vsum, scal = wsf+9216:
//   scal[0]=psum, scal[2..5]=counts, scal[9]=done counter
// Zeroed by kernel A's blocks 0..39 (no separate memset dispatch: ~20us/dispatch
// of graph overhead measured in R1-R4).

// ---------------- kernel A: zero accum region; normalize -> znb bf16 ------
// One wave per row pair (zi[i], zj[i]). 4096 waves = 1024 blocks. No atomics
// here (zeroing blocks and worker blocks must not race within this kernel).
__global__ __launch_bounds__(256) void norm_kernel(const float* __restrict__ zi,
                                                   const float* __restrict__ zj,
                                                   float* __restrict__ wsf,
                                                   unsigned short* __restrict__ znb) {
  if (blockIdx.x < 40) wsf[blockIdx.x * 256 + threadIdx.x] = 0.f;
  const int lane = threadIdx.x & 63, wave = threadIdx.x >> 6;
  const int i = blockIdx.x * 4 + wave;

  float4 a = ((const float4*)(zi + (size_t)i * DD))[lane];
  float4 b = ((const float4*)(zj + (size_t)i * DD))[lane];
  float sa = a.x * a.x + a.y * a.y + a.z * a.z + a.w * a.w;
  float sb = b.x * b.x + b.y * b.y + b.z * b.z + b.w * b.w;
#pragma unroll
  for (int m = 32; m >= 1; m >>= 1) {
    sa += __shfl_xor(sa, m);
    sb += __shfl_xor(sb, m);
  }
  float ra = 1.0f / fmaxf(sqrtf(sa), 1e-8f);
  float rb = 1.0f / fmaxf(sqrtf(sb), 1e-8f);
  ushort4 oa, ob;
  oa.x = f2bf(a.x * ra); oa.y = f2bf(a.y * ra); oa.z = f2bf(a.z * ra); oa.w = f2bf(a.w * ra);
  ob.x = f2bf(b.x * rb); ob.y = f2bf(b.y * rb); ob.z = f2bf(b.z * rb); ob.w = f2bf(b.w * rb);
  ((ushort4*)(znb + (size_t)i * DD))[lane] = oa;
  ((ushort4*)(znb + (size_t)(i + NB) * DD))[lane] = ob;
}

// ---------------- kernel B: gsum blocks + one tile per block + tail -------
// blocks 0..15: group sums/counts. blocks 16..2095: one symmetric S-tile each
// (static assignment: restores R1's inter-block pipelining that the R4 steal
// loop destroyed). pos extracted as the trace of tiles with tc == tr+32.
// Last block to arrive on the done counter computes the scalar tail.
__global__ __launch_bounds__(256, 3) void main_kernel(const int* __restrict__ sf,
                                                      float* __restrict__ wsf,
                                                      const unsigned short* __restrict__ znb,
                                                      float* __restrict__ out) {
  __shared__ __align__(16) unsigned short As[2][4096];  // 2 x 8KB
  __shared__ __align__(16) unsigned short Bs[2][4096];
  __shared__ float sred[32];
  __shared__ int sh_last;

  float* den = wsf;
  float* vsum = wsf + 8192;
  float* scal = wsf + 9216;
  unsigned* done = (unsigned*)(scal + 9);

  const int tid = threadIdx.x;
  const int lane = tid & 63, wave = tid >> 6;

  if (blockIdx.x < GSUM_BLOCKS) {
    // ---- gsum role: 256 rows each (znb valid across kernel boundary) ----
    const int r0 = blockIdx.x * 256;
    {
      int g = sf[r0 + tid];
#pragma unroll
      for (int q = 0; q < 4; ++q) {
        unsigned long long m = __ballot(g == q);
        if (lane == 0) unsafeAtomicAdd(&scal[2 + q], (float)__popcll(m));
      }
    }
    float acc[4][4];
#pragma unroll
    for (int q = 0; q < 4; ++q)
#pragma unroll
      for (int e = 0; e < 4; ++e) acc[q][e] = 0.f;
    const int rw = r0 + wave * 64;
    for (int k = 0; k < 64; ++k) {
      int row = rw + k;
      int g = sf[row];
      ushort4 v = ((const ushort4*)(znb + (size_t)row * DD))[lane];
      float f0 = bf2f(v.x), f1 = bf2f(v.y), f2 = bf2f(v.z), f3 = bf2f(v.w);
#pragma unroll
      for (int q = 0; q < 4; ++q) {
        acc[q][0] += (g == q) ? f0 : 0.f;
        acc[q][1] += (g == q) ? f1 : 0.f;
        acc[q][2] += (g == q) ? f2 : 0.f;
        acc[q][3] += (g == q) ? f3 : 0.f;
      }
    }
#pragma unroll
    for (int q = 0; q < 4; ++q)
#pragma unroll
      for (int e = 0; e < 4; ++e)
        unsafeAtomicAdd(&vsum[q * DD + lane * 4 + e], acc[q][e]);
  } else {
    // ---- one symmetric den tile ----------------------------------------
    unsigned t = blockIdx.x - GSUM_BLOCKS;
    unsigned tr = 0;
    while (t >= 64u - tr) { t -= 64u - tr; ++tr; }
    unsigned tc = tr + t;
    const bool diag = (tr == tc);
    const size_t rowbase = (size_t)tr * 128, colbase = (size_t)tc * 128;

    const int u = lane >> 3;
    const int cp = (lane & 7) ^ u;
    const int ri = 2 * u + (cp >> 2);
    const int kelem = (cp & 3) * 8;
    const int slot = ((((lane & 1) << 2) | (lane >> 4)) ^ ((lane >> 1) & 7));
    const int fragoff = ((lane & 15) >> 1) * 128 + slot * 16;
    const int wrow = wave & 1, wcol = wave >> 1;
    const char* Abase = (const char*)&As[0][0];
    const char* Bbase = (const char*)&Bs[0][0];

    f32x4 zero = {0.f, 0.f, 0.f, 0.f};
    f32x4 acc[4][4];
#pragma unroll
    for (int i = 0; i < 4; ++i)
#pragma unroll
      for (int j = 0; j < 4; ++j) acc[i][j] = zero;

    auto stage = [&](int kt, int buf) {
#pragma unroll
      for (int j = 0; j < 2; ++j) {
        int is = wave * 2 + j;
        const unsigned short* gpa = znb + (rowbase + is * 16 + ri) * DD + kt * 32 + kelem;
        __builtin_amdgcn_global_load_lds((gvoid_t*)gpa, (lvoid_t*)&As[buf][is * 512], 16, 0, 0);
        if (!diag) {
          const unsigned short* gpb = znb + (colbase + is * 16 + ri) * DD + kt * 32 + kelem;
          __builtin_amdgcn_global_load_lds((gvoid_t*)gpb, (lvoid_t*)&Bs[buf][is * 512], 16, 0, 0);
        }
      }
    };

    stage(0, 0);
    __syncthreads();
    const char* Bb = diag ? Abase : Bbase;
#pragma unroll
    for (int kt = 0; kt < 8; ++kt) {
      if (kt < 7) stage(kt + 1, (kt + 1) & 1);
      const int buf = kt & 1;
      short8 af[4], bfr[4];
#pragma unroll
      for (int mi = 0; mi < 4; ++mi)
        af[mi] = *(const short8*)(Abase + buf * 8192 + wrow * 4096 + mi * 1024 + fragoff);
#pragma unroll
      for (int ni = 0; ni < 4; ++ni)
        bfr[ni] = *(const short8*)(Bb + buf * 8192 + wcol * 4096 + ni * 1024 + fragoff);
#pragma unroll
      for (int mi = 0; mi < 4; ++mi)
#pragma unroll
        for (int ni = 0; ni < 4; ++ni)
          acc[mi][ni] = __builtin_amdgcn_mfma_f32_16x16x32_bf16(af[mi], bfr[ni], acc[mi][ni], 0, 0, 0);
      __syncthreads();
    }

    // epilogue: e = exp(2S); row sums always; col sums for off-diag tiles.
    // C layout: col = lane&15, row = (lane>>4)*4 + reg.
    float rsum[4][4];
    float csum[4] = {0.f, 0.f, 0.f, 0.f};
#pragma unroll
    for (int mi = 0; mi < 4; ++mi)
#pragma unroll
      for (int r = 0; r < 4; ++r) rsum[mi][r] = 0.f;
#pragma unroll
    for (int mi = 0; mi < 4; ++mi)
#pragma unroll
      for (int ni = 0; ni < 4; ++ni)
#pragma unroll
        for (int r = 0; r < 4; ++r) {
          float e = __expf(2.0f * acc[mi][ni][r]);
          rsum[mi][r] += e;
          csum[ni] += e;
        }
#pragma unroll
    for (int m = 1; m < 16; m <<= 1)
#pragma unroll
      for (int mi = 0; mi < 4; ++mi)
#pragma unroll
        for (int r = 0; r < 4; ++r) rsum[mi][r] += __shfl_xor(rsum[mi][r], m);
    if ((lane & 15) == 0) {
      int h = lane >> 4;
#pragma unroll
      for (int mi = 0; mi < 4; ++mi)
#pragma unroll
        for (int r = 0; r < 4; ++r)
          unsafeAtomicAdd(&den[rowbase + wrow * 64 + mi * 16 + h * 4 + r], rsum[mi][r]);
    }
    if (!diag) {
#pragma unroll
      for (int m = 16; m < 64; m <<= 1)
#pragma unroll
        for (int ni = 0; ni < 4; ++ni) csum[ni] += __shfl_xor(csum[ni], m);
      if (lane < 16) {
#pragma unroll
        for (int ni = 0; ni < 4; ++ni)
          unsafeAtomicAdd(&den[colbase + wcol * 64 + ni * 16 + lane], csum[ni]);
      }
    }
    // pos trace: tiles (tr, tr+32) hold S[i][i+B] on their local diagonal.
    if (tc == tr + 32u && wrow == wcol) {
      float tacc = 0.f;
      int c = lane & 15, quad = lane >> 4;
      bool sel = (c >> 2) == quad;
#pragma unroll
      for (int mi = 0; mi < 4; ++mi)
#pragma unroll
        for (int r = 0; r < 4; ++r)
          tacc += (sel && ((c & 3) == r)) ? acc[mi][mi][r] : 0.f;
#pragma unroll
      for (int m = 32; m >= 1; m >>= 1) tacc += __shfl_xor(tacc, m);
      if (lane == 0) unsafeAtomicAdd(&scal[0], tacc);
    }
  }

  // ---- arrive; LAST block computes the tail ------------------------------
  __syncthreads();
  if (tid == 0) {
    unsigned old = __hip_atomic_fetch_add(done, 1u, __ATOMIC_ACQ_REL, __HIP_MEMORY_SCOPE_AGENT);
    sh_last = (old == gridDim.x - 1) ? 1 : 0;
  }
  __syncthreads();
  if (!sh_last) return;
  __builtin_amdgcn_fence(__ATOMIC_ACQUIRE, "agent");

  // tail: log-reduce den, fairness from vsum, finalize
  const float e2 = __expf(2.0f);
  float ls = 0.f;
  for (int i = tid; i < TWOB; i += 256) ls += __logf(den[i] - e2);
#pragma unroll
  for (int m = 32; m >= 1; m >>= 1) ls += __shfl_xor(ls, m);
  if (lane == 0) sred[wave] = ls;
  float gp[4];
#pragma unroll
  for (int g = 0; g < 4; ++g) {
    float v = vsum[g * DD + tid];
    gp[g] = v * v;
#pragma unroll
    for (int m = 32; m >= 1; m >>= 1) gp[g] += __shfl_xor(gp[g], m);
  }
  if (lane == 0) {
#pragma unroll
    for (int g = 0; g < 4; ++g) sred[4 + wave * 4 + g] = gp[g];
  }
  __syncthreads();
  if (tid == 0) {
    float lsum = sred[0] + sred[1] + sred[2] + sred[3];
    float psum = scal[0];
    float contrastive = (lsum - 4.0f * psum) / (float)TWOB;
    float fsum = 0.f;
    int uniq = 0;
#pragma unroll
    for (int q = 0; q < 4; ++q) {
      float gsq = sred[4 + q] + sred[8 + q] + sred[12 + q] + sred[16 + q];
      float c = scal[2 + q];
      if (c > 0.5f) uniq++;
      if (c > 1.5f) fsum += gsq / (c * (c - 1.0f));
    }
    out[0] = contrastive + 0.1f * (fsum / (uniq > 0 ? (float)uniq : 1.0f));
  }
}

extern "C" void kernel_launch(void* const* d_in, const int* in_sizes, int n_in,
                              void* d_out, int out_size, void* d_ws, size_t ws_size,
                              hipStream_t stream) {
  const float* zi = (const float*)d_in[0];
  const float* zj = (const float*)d_in[1];
  const int* sf = (const int*)d_in[2];
  float* out = (float*)d_out;
  char* ws = (char*)d_ws;
  float* wsf = (float*)ws;                              // den/vsum/scal region
  unsigned short* znb = (unsigned short*)(ws + 65536);  // 8192x256 bf16 (4MB)

  hipLaunchKernelGGL(norm_kernel, dim3(1024), dim3(256), 0, stream, zi, zj, wsf, znb);
  hipLaunchKernelGGL(main_kernel, dim3(GRID_B), dim3(256), 0, stream, sf, wsf, znb, out);
}

// Round 6
// 139.894 us; speedup vs baseline: 2.5450x; 1.0502x over previous
//
#include <hip/hip_runtime.h>
#include <hip/hip_bf16.h>

typedef __attribute__((ext_vector_type(8))) short short8;
typedef __attribute__((ext_vector_type(4))) float f32x4;
typedef __attribute__((address_space(1))) const void gvoid_t;
typedef __attribute__((address_space(3))) void lvoid_t;

#define NB 4096   // B
#define DD 256    // D
#define TWOB 8192
#define NTILES 2080u   // 64*65/2 symmetric 128x128 tiles
#define GSUM_BLOCKS 16
#define GRID_B (NTILES + GSUM_BLOCKS)

__device__ __forceinline__ unsigned short f2bf(float f) {
  unsigned int u = __float_as_uint(f);
  u += 0x7fffu + ((u >> 16) & 1u);
  return (unsigned short)(u >> 16);
}
__device__ __forceinline__ float bf2f(unsigned short s) {
  return __uint_as_float(((unsigned int)s) << 16);
}

// ws float layout: [0..8191] den, [8192..9215] vsum, scal = wsf+9216:
//   scal[0]=psum, scal[2..5]=counts, scal[9]=done counter
// Zeroed by kernel A's blocks 0..39.

// ---------------- kernel A: zero accum region; normalize -> znb bf16 ------
__global__ __launch_bounds__(256) void norm_kernel(const float* __restrict__ zi,
                                                   const float* __restrict__ zj,
                                                   float* __restrict__ wsf,
                                                   unsigned short* __restrict__ znb) {
  if (blockIdx.x < 40) wsf[blockIdx.x * 256 + threadIdx.x] = 0.f;
  const int lane = threadIdx.x & 63, wave = threadIdx.x >> 6;
  const int i = blockIdx.x * 4 + wave;

  float4 a = ((const float4*)(zi + (size_t)i * DD))[lane];
  float4 b = ((const float4*)(zj + (size_t)i * DD))[lane];
  float sa = a.x * a.x + a.y * a.y + a.z * a.z + a.w * a.w;
  float sb = b.x * b.x + b.y * b.y + b.z * b.z + b.w * b.w;
#pragma unroll
  for (int m = 32; m >= 1; m >>= 1) {
    sa += __shfl_xor(sa, m);
    sb += __shfl_xor(sb, m);
  }
  float ra = 1.0f / fmaxf(sqrtf(sa), 1e-8f);
  float rb = 1.0f / fmaxf(sqrtf(sb), 1e-8f);
  ushort4 oa, ob;
  oa.x = f2bf(a.x * ra); oa.y = f2bf(a.y * ra); oa.z = f2bf(a.z * ra); oa.w = f2bf(a.w * ra);
  ob.x = f2bf(b.x * rb); ob.y = f2bf(b.y * rb); ob.z = f2bf(b.z * rb); ob.w = f2bf(b.w * rb);
  ((ushort4*)(znb + (size_t)i * DD))[lane] = oa;
  ((ushort4*)(znb + (size_t)(i + NB) * DD))[lane] = ob;
}

// ---------------- kernel B: gsum blocks + one tile per block + tail -------
// R5 post-mortem: the ACQ_REL arrive emitted buffer_inv (full L1/L2
// invalidate) per block exit -> znb thrashed out of L2 (L3 absorbed the
// re-fetches, invisible in FETCH_SIZE), 3x per-tile latency. Arrive is now
// RELEASE-only (s_waitcnt, no cache op); the single acquire fence
// (buffer_inv) runs only in the last block before it reads den/vsum.
__global__ __launch_bounds__(256, 3) void main_kernel(const int* __restrict__ sf,
                                                      float* __restrict__ wsf,
                                                      const unsigned short* __restrict__ znb,
                                                      float* __restrict__ out) {
  __shared__ __align__(16) unsigned short As[2][4096];  // 2 x 8KB
  __shared__ __align__(16) unsigned short Bs[2][4096];
  __shared__ float sred[32];
  __shared__ int sh_last;

  float* den = wsf;
  float* vsum = wsf + 8192;
  float* scal = wsf + 9216;
  unsigned* done = (unsigned*)(scal + 9);

  const int tid = threadIdx.x;
  const int lane = tid & 63, wave = tid >> 6;

  if (blockIdx.x < GSUM_BLOCKS) {
    // ---- gsum role: 256 rows each (znb valid across kernel boundary) ----
    const int r0 = blockIdx.x * 256;
    {
      int g = sf[r0 + tid];
#pragma unroll
      for (int q = 0; q < 4; ++q) {
        unsigned long long m = __ballot(g == q);
        if (lane == 0) unsafeAtomicAdd(&scal[2 + q], (float)__popcll(m));
      }
    }
    float acc[4][4];
#pragma unroll
    for (int q = 0; q < 4; ++q)
#pragma unroll
      for (int e = 0; e < 4; ++e) acc[q][e] = 0.f;
    const int rw = r0 + wave * 64;
    for (int k = 0; k < 64; ++k) {
      int row = rw + k;
      int g = sf[row];
      ushort4 v = ((const ushort4*)(znb + (size_t)row * DD))[lane];
      float f0 = bf2f(v.x), f1 = bf2f(v.y), f2 = bf2f(v.z), f3 = bf2f(v.w);
#pragma unroll
      for (int q = 0; q < 4; ++q) {
        acc[q][0] += (g == q) ? f0 : 0.f;
        acc[q][1] += (g == q) ? f1 : 0.f;
        acc[q][2] += (g == q) ? f2 : 0.f;
        acc[q][3] += (g == q) ? f3 : 0.f;
      }
    }
#pragma unroll
    for (int q = 0; q < 4; ++q)
#pragma unroll
      for (int e = 0; e < 4; ++e)
        unsafeAtomicAdd(&vsum[q * DD + lane * 4 + e], acc[q][e]);
  } else {
    // ---- one symmetric den tile ----------------------------------------
    unsigned t = blockIdx.x - GSUM_BLOCKS;
    unsigned tr = 0;
    while (t >= 64u - tr) { t -= 64u - tr; ++tr; }
    unsigned tc = tr + t;
    const bool diag = (tr == tc);
    const size_t rowbase = (size_t)tr * 128, colbase = (size_t)tc * 128;

    const int u = lane >> 3;
    const int cp = (lane & 7) ^ u;
    const int ri = 2 * u + (cp >> 2);
    const int kelem = (cp & 3) * 8;
    const int slot = ((((lane & 1) << 2) | (lane >> 4)) ^ ((lane >> 1) & 7));
    const int fragoff = ((lane & 15) >> 1) * 128 + slot * 16;
    const int wrow = wave & 1, wcol = wave >> 1;
    const char* Abase = (const char*)&As[0][0];
    const char* Bbase = (const char*)&Bs[0][0];

    f32x4 zero = {0.f, 0.f, 0.f, 0.f};
    f32x4 acc[4][4];
#pragma unroll
    for (int i = 0; i < 4; ++i)
#pragma unroll
      for (int j = 0; j < 4; ++j) acc[i][j] = zero;

    auto stage = [&](int kt, int buf) {
#pragma unroll
      for (int j = 0; j < 2; ++j) {
        int is = wave * 2 + j;
        const unsigned short* gpa = znb + (rowbase + is * 16 + ri) * DD + kt * 32 + kelem;
        __builtin_amdgcn_global_load_lds((gvoid_t*)gpa, (lvoid_t*)&As[buf][is * 512], 16, 0, 0);
        if (!diag) {
          const unsigned short* gpb = znb + (colbase + is * 16 + ri) * DD + kt * 32 + kelem;
          __builtin_amdgcn_global_load_lds((gvoid_t*)gpb, (lvoid_t*)&Bs[buf][is * 512], 16, 0, 0);
        }
      }
    };

    stage(0, 0);
    __syncthreads();
    const char* Bb = diag ? Abase : Bbase;
#pragma unroll
    for (int kt = 0; kt < 8; ++kt) {
      if (kt < 7) stage(kt + 1, (kt + 1) & 1);
      const int buf = kt & 1;
      short8 af[4], bfr[4];
#pragma unroll
      for (int mi = 0; mi < 4; ++mi)
        af[mi] = *(const short8*)(Abase + buf * 8192 + wrow * 4096 + mi * 1024 + fragoff);
#pragma unroll
      for (int ni = 0; ni < 4; ++ni)
        bfr[ni] = *(const short8*)(Bb + buf * 8192 + wcol * 4096 + ni * 1024 + fragoff);
#pragma unroll
      for (int mi = 0; mi < 4; ++mi)
#pragma unroll
        for (int ni = 0; ni < 4; ++ni)
          acc[mi][ni] = __builtin_amdgcn_mfma_f32_16x16x32_bf16(af[mi], bfr[ni], acc[mi][ni], 0, 0, 0);
      __syncthreads();
    }

    // epilogue: e = exp(2S); row sums always; col sums for off-diag tiles.
    // C layout: col = lane&15, row = (lane>>4)*4 + reg.
    float rsum[4][4];
    float csum[4] = {0.f, 0.f, 0.f, 0.f};
#pragma unroll
    for (int mi = 0; mi < 4; ++mi)
#pragma unroll
      for (int r = 0; r < 4; ++r) rsum[mi][r] = 0.f;
#pragma unroll
    for (int mi = 0; mi < 4; ++mi)
#pragma unroll
      for (int ni = 0; ni < 4; ++ni)
#pragma unroll
        for (int r = 0; r < 4; ++r) {
          float e = __expf(2.0f * acc[mi][ni][r]);
          rsum[mi][r] += e;
          csum[ni] += e;
        }
#pragma unroll
    for (int m = 1; m < 16; m <<= 1)
#pragma unroll
      for (int mi = 0; mi < 4; ++mi)
#pragma unroll
        for (int r = 0; r < 4; ++r) rsum[mi][r] += __shfl_xor(rsum[mi][r], m);
    if ((lane & 15) == 0) {
      int h = lane >> 4;
#pragma unroll
      for (int mi = 0; mi < 4; ++mi)
#pragma unroll
        for (int r = 0; r < 4; ++r)
          unsafeAtomicAdd(&den[rowbase + wrow * 64 + mi * 16 + h * 4 + r], rsum[mi][r]);
    }
    if (!diag) {
#pragma unroll
      for (int m = 16; m < 64; m <<= 1)
#pragma unroll
        for (int ni = 0; ni < 4; ++ni) csum[ni] += __shfl_xor(csum[ni], m);
      if (lane < 16) {
#pragma unroll
        for (int ni = 0; ni < 4; ++ni)
          unsafeAtomicAdd(&den[colbase + wcol * 64 + ni * 16 + lane], csum[ni]);
      }
    }
    // pos trace: tiles (tr, tr+32) hold S[i][i+B] on their local diagonal.
    if (tc == tr + 32u && wrow == wcol) {
      float tacc = 0.f;
      int c = lane & 15, quad = lane >> 4;
      bool sel = (c >> 2) == quad;
#pragma unroll
      for (int mi = 0; mi < 4; ++mi)
#pragma unroll
        for (int r = 0; r < 4; ++r)
          tacc += (sel && ((c & 3) == r)) ? acc[mi][mi][r] : 0.f;
#pragma unroll
      for (int m = 32; m >= 1; m >>= 1) tacc += __shfl_xor(tacc, m);
      if (lane == 0) unsafeAtomicAdd(&scal[0], tacc);
    }
  }

  // ---- arrive (RELEASE only: s_waitcnt, no buffer_inv); last block tails --
  __syncthreads();  // drains every wave's vmem (compiler emits waitcnt vmcnt(0))
  if (tid == 0) {
    unsigned old = __hip_atomic_fetch_add(done, 1u, __ATOMIC_RELEASE, __HIP_MEMORY_SCOPE_AGENT);
    sh_last = (old == gridDim.x - 1) ? 1 : 0;
  }
  __syncthreads();
  if (!sh_last) return;
  __builtin_amdgcn_fence(__ATOMIC_ACQUIRE, "agent");  // single buffer_inv, last block only

  // tail: log-reduce den, fairness from vsum, finalize
  const float e2 = __expf(2.0f);
  float ls = 0.f;
  for (int i = tid; i < TWOB; i += 256) ls += __logf(den[i] - e2);
#pragma unroll
  for (int m = 32; m >= 1; m >>= 1) ls += __shfl_xor(ls, m);
  if (lane == 0) sred[wave] = ls;
  float gp[4];
#pragma unroll
  for (int g = 0; g < 4; ++g) {
    float v = vsum[g * DD + tid];
    gp[g] = v * v;
#pragma unroll
    for (int m = 32; m >= 1; m >>= 1) gp[g] += __shfl_xor(gp[g], m);
  }
  if (lane == 0) {
#pragma unroll
    for (int g = 0; g < 4; ++g) sred[4 + wave * 4 + g] = gp[g];
  }
  __syncthreads();
  if (tid == 0) {
    float lsum = sred[0] + sred[1] + sred[2] + sred[3];
    float psum = scal[0];
    float contrastive = (lsum - 4.0f * psum) / (float)TWOB;
    float fsum = 0.f;
    int uniq = 0;
#pragma unroll
    for (int q = 0; q < 4; ++q) {
      float gsq = sred[4 + q] + sred[8 + q] + sred[12 + q] + sred[16 + q];
      float c = scal[2 + q];
      if (c > 0.5f) uniq++;
      if (c > 1.5f) fsum += gsq / (c * (c - 1.0f));
    }
    out[0] = contrastive + 0.1f * (fsum / (uniq > 0 ? (float)uniq : 1.0f));
  }
}

extern "C" void kernel_launch(void* const* d_in, const int* in_sizes, int n_in,
                              void* d_out, int out_size, void* d_ws, size_t ws_size,
                              hipStream_t stream) {
  const float* zi = (const float*)d_in[0];
  const float* zj = (const float*)d_in[1];
  const int* sf = (const int*)d_in[2];
  float* out = (float*)d_out;
  char* ws = (char*)d_ws;
  float* wsf = (float*)ws;                              // den/vsum/scal region
  unsigned short* znb = (unsigned short*)(ws + 65536);  // 8192x256 bf16 (4MB)

  hipLaunchKernelGGL(norm_kernel, dim3(1024), dim3(256), 0, stream, zi, zj, wsf, znb);
  hipLaunchKernelGGL(main_kernel, dim3(GRID_B), dim3(256), 0, stream, sf, wsf, znb, out);
}